// Round 4
// baseline (218.586 us; speedup 1.0000x reference)
//
#include <hip/hip_runtime.h>
#include <hip/hip_bf16.h>

// ROI Align (FPN, 4 levels, PH=PW=7, SR=2). All-fp32 I/O (per reference).
// Theory locked by R0-R3 evidence: R3's NaN proves features are fp32;
// R2's 5.06 was bf16-written-to-fp32-output scrambling; R1's fault was
// bf16-misread rois -> wild batch pointer.
// One thread per output element (k, c, ph, pw): 4 subsamples x 4 bilinear
// corners = 16 gathers from the (b, c) feature plane of the ROI's level.
// All index math clamped -> no fault possible under any dtype surprise.

#define NUM_CH 256

__global__ __launch_bounds__(256) void roi_align_kernel(
    const float* __restrict__ f0,
    const float* __restrict__ f1,
    const float* __restrict__ f2,
    const float* __restrict__ f3,
    const float* __restrict__ rois_f,
    const int* __restrict__ level,
    float* __restrict__ out,
    int total)
{
    int e = blockIdx.x * blockDim.x + threadIdx.x;
    if (e >= total) return;

    int p  = e % 49;           // output pixel
    int t  = e / 49;
    int c  = t % NUM_CH;       // channel
    int k  = t / NUM_CH;       // roi
    int ph = p / 7;
    int pw = p % 7;

    int lvl = level[k];
    const float* f;
    int H, W;
    float scale;
    if (lvl == 0)      { f = f0; H = 200; W = 200; scale = 0.25f;    }
    else if (lvl == 1) { f = f1; H = 100; W = 100; scale = 0.125f;   }
    else if (lvl == 2) { f = f2; H = 50;  W = 50;  scale = 0.0625f;  }
    else               { f = f3; H = 25;  W = 25;  scale = 0.03125f; }

    // Adaptive rois read: genuine fp32 rois has column 0 exactly 0.0/1.0
    // (batch index). Otherwise the buffer would be bf16 -> fallback path.
    const float* rf = rois_f + (size_t)k * 5;
    float r0 = rf[0];
    float x1, y1, x2, y2;
    if (r0 == 0.0f || r0 == 1.0f) {
        x1 = rf[1]; y1 = rf[2]; x2 = rf[3]; y2 = rf[4];
    } else {
        const __hip_bfloat16* rb = (const __hip_bfloat16*)rois_f + (size_t)k * 5;
        r0 = __bfloat162float(rb[0]);
        x1 = __bfloat162float(rb[1]);
        y1 = __bfloat162float(rb[2]);
        x2 = __bfloat162float(rb[3]);
        y2 = __bfloat162float(rb[4]);
    }
    x1 *= scale; y1 *= scale; x2 *= scale; y2 *= scale;

    int b = (int)r0;
    b = (b < 0) ? 0 : ((b > 1) ? 1 : b);   // defensive clamp: B == 2

    float roi_w = fmaxf(x2 - x1, 1.0f);
    float roi_h = fmaxf(y2 - y1, 1.0f);
    float bw = roi_w * (1.0f / 7.0f);
    float bh = roi_h * (1.0f / 7.0f);

    const float* base = f + ((size_t)b * NUM_CH + c) * (size_t)(H * W);

    float acc = 0.0f;
    #pragma unroll
    for (int sy = 0; sy < 2; ++sy) {
        // y sample coordinate: y1 + ph*bh + (sy+0.5)*(bh/2)
        float y = y1 + (float)ph * bh + ((float)sy + 0.5f) * (bh * 0.5f);
        if (!(y > -1.0f && y < (float)H)) continue;   // invalid -> contributes 0
        float yc = fmaxf(y, 0.0f);
        int   yl = min((int)yc, H - 1);
        int   yh = min(yl + 1, H - 1);
        float ly = (yl >= H - 1) ? 0.0f : (yc - (float)yl);
        float hy = 1.0f - ly;
        #pragma unroll
        for (int sx = 0; sx < 2; ++sx) {
            float x = x1 + (float)pw * bw + ((float)sx + 0.5f) * (bw * 0.5f);
            if (!(x > -1.0f && x < (float)W)) continue;
            float xc = fmaxf(x, 0.0f);
            int   xl = min((int)xc, W - 1);
            int   xh = min(xl + 1, W - 1);
            float lx = (xl >= W - 1) ? 0.0f : (xc - (float)xl);
            float hx = 1.0f - lx;

            float v00 = base[yl * W + xl];
            float v01 = base[yl * W + xh];
            float v10 = base[yh * W + xl];
            float v11 = base[yh * W + xh];
            acc += hy * (hx * v00 + lx * v01) + ly * (hx * v10 + lx * v11);
        }
    }

    // mean over the 2x2 subsample grid (invalid samples count as 0)
    out[e] = acc * 0.25f;
}

extern "C" void kernel_launch(void* const* d_in, const int* in_sizes, int n_in,
                              void* d_out, int out_size, void* d_ws, size_t ws_size,
                              hipStream_t stream) {
    const float* f0   = (const float*)d_in[0];
    const float* f1   = (const float*)d_in[1];
    const float* f2   = (const float*)d_in[2];
    const float* f3   = (const float*)d_in[3];
    const float* rois = (const float*)d_in[4];
    // d_in[5] = rois_counts (unused: level[] fully determines routing)
    const int* level = (const int*)d_in[6];
    float* out = (float*)d_out;

    int total = out_size;  // K * 256 * 49
    int threads = 256;
    int blocks = (total + threads - 1) / threads;
    roi_align_kernel<<<blocks, threads, 0, stream>>>(f0, f1, f2, f3, rois, level, out, total);
}